// Round 8
// baseline (17.248 us; speedup 1.0000x reference)
//
#include <hip/hip_runtime.h>
#include <cstddef>

#define POOL 7
#define NEGV (-3e38f)

__device__ __forceinline__ float4 fmax4(float4 a, float4 b) {
    return make_float4(fmaxf(a.x, b.x), fmaxf(a.y, b.y),
                       fmaxf(a.z, b.z), fmaxf(a.w, b.w));
}

// Load & max-reduce exactly N rows of the lane's quad column. Loads batched
// (<=5 in flight) before any fmax; addresses exact (no clamping needed).
template<int N>
__device__ __forceinline__ float4 colmax_n(const float4* __restrict__ fp4,
                                           int ys, int xq) {
    constexpr int B1 = (N <= 5) ? N : (N + 1) / 2;
    float4 m = make_float4(NEGV, NEGV, NEGV, NEGV);
#pragma unroll
    for (int bb = 0; bb < N; bb += B1) {
        float4 t[B1];
#pragma unroll
        for (int k = 0; k < B1; ++k)
            if (bb + k < N) t[k] = fp4[((ys + bb + k) << 4) + xq];
#pragma unroll
        for (int k = 0; k < B1; ++k)
            if (bb + k < N) m = fmax4(m, t[k]);
    }
    return m;
}

// Exact-width LDS row reduce; clamped duplicate reads are max-idempotent.
template<int KW>
__device__ __forceinline__ float rowmax_lds(const float* __restrict__ rrow,
                                            int xs, int xec) {
    float t[KW];
#pragma unroll
    for (int k = 0; k < KW; ++k) t[k] = rrow[min(xs + k, xec)];
    float m = t[0];
#pragma unroll
    for (int k = 1; k < KW; ++k) m = fmaxf(m, t[k]);
    return m;
}

// Block = one (ROI, 4-channel group); its 4 waves statically split the 7
// pooled rows: wave wv handles windows {2wv, 2wv+1} (wv=3 -> {6} only).
// Per-wave serial chain = 2 load-waits instead of 7; 32768 waves total keep
// every SIMD's issue slots fed while chains wait. No barriers, no atomics.
__global__ __launch_bounds__(256) void roi_pool_kernel(
    const float* __restrict__ feat, const float4* __restrict__ rois4,
    float* __restrict__ out)
{
    const int tid  = threadIdx.x;
    const int lane = tid & 63;
    const int wv   = tid >> 6;
    const int bid  = blockIdx.x;
    // bid = br*64 + c4: XCD = bid%8 = c4%8 -> each XCD owns a fixed 32-channel
    // slice (2 MB feature working set, L2-resident).
    const int br = bid >> 6;            // b*64 + r
    const int c4 = bid & 63;            // 4-channel group
    const int b  = br >> 6;
    const int cs = lane >> 4;           // channel slot 0..3
    const int lx = lane & 15;           // quad slot 0..15

    // ---- ROI decode; force SGPR so downstream address math scalarizes ----
    const float4 rv = rois4[br];
    const int px = __builtin_amdgcn_readfirstlane(__float2int_rn(rv.x * 0.0625f));
    const int py = __builtin_amdgcn_readfirstlane(__float2int_rn(rv.y * 0.0625f));
    const int qx = __builtin_amdgcn_readfirstlane(__float2int_rn(rv.z * 0.0625f));
    const int qy = __builtin_amdgcn_readfirstlane(__float2int_rn(rv.w * 0.0625f));
    const int roi_w = max(qx - px + 1, 1);
    const int roi_h = max(qy - py + 1, 1);
    const int psw = (roi_w + POOL - 1) / POOL;
    const int psh = (roi_h + POOL - 1) / POOL;
    const int pad_l = (psw * POOL - roi_w) >> 1;
    const int pad_t = (psh * POOL - roi_h) >> 1;

    // quad coverage of [px,qx]; clamped duplicate lanes hit the same lines
    const int qbase = px >> 2;
    const int nq    = (qx >> 2) - qbase + 1;
    const int xq    = qbase + min(lx, nq - 1);

    const int c = (c4 << 2) + cs;
    const float4* fp4 = (const float4*)feat + ((size_t)((b << 8) + c) << 10);

    __shared__ __attribute__((aligned(16))) float lds[4][2][4][64];
    float* ldsw = &lds[wv][0][0][0];

    // ---- phase-2 x-window setup (identical for both of this wave's rows) ----
    const bool active = lane < 28;
    const int li  = min(lane, 27);
    const int i7  = li / 7;             // channel slot
    const int j7  = li - i7 * 7;        // pooled column
    const int pxl = px & 3;
    const int lox = max(j7 * psw - pad_l, 0);
    const int hix = min((j7 + 1) * psw - pad_l, roi_w) - 1;
    const int xs  = pxl + lox;
    const int xe  = pxl + hix;          // < xs if empty
    const int xec = max(xe, 0);
    const bool xempty = xe < xs;
    const bool padc = (j7 * psw < pad_l) | ((j7 + 1) * psw > pad_l + roi_w);
    const size_t obase = ((size_t)(br << 8) + (c4 << 2) + i7) * 49 + j7;

#pragma unroll
    for (int s = 0; s < 2; ++s) {
        const int i = (wv << 1) + s;    // this wave's pooled row
        if (i <= 6) {
            // exact y-window of pooled row i
            const int lo = max(i * psh - pad_t, 0);
            const int hi = min((i + 1) * psh - pad_t, roi_h) - 1;
            const int wlen = hi - lo + 1;       // <=0 if empty window
            const int ys = py + lo;

            float4 m4 = make_float4(NEGV, NEGV, NEGV, NEGV);
            switch (wlen) {
                case 1:  m4 = colmax_n<1 >(fp4, ys, xq); break;
                case 2:  m4 = colmax_n<2 >(fp4, ys, xq); break;
                case 3:  m4 = colmax_n<3 >(fp4, ys, xq); break;
                case 4:  m4 = colmax_n<4 >(fp4, ys, xq); break;
                case 5:  m4 = colmax_n<5 >(fp4, ys, xq); break;
                case 6:  m4 = colmax_n<6 >(fp4, ys, xq); break;
                case 7:  m4 = colmax_n<7 >(fp4, ys, xq); break;
                case 8:  m4 = colmax_n<8 >(fp4, ys, xq); break;
                case 9:  m4 = colmax_n<9 >(fp4, ys, xq); break;
                case 10: m4 = colmax_n<10>(fp4, ys, xq); break;
                default: break;
            }

            // LDS handoff (same wave, in-order DS pipe: no barrier)
            *(float4*)(ldsw + (((s << 2) + cs) << 6) + ((xq - qbase) << 2)) = m4;

            // reduce along x, pad rule, store
            const float* rrow = ldsw + (((s << 2) + i7) << 6);
            float m;
            switch (psw) {
                case 1:  m = rowmax_lds<1 >(rrow, xs, xec); break;
                case 2:  m = rowmax_lds<2 >(rrow, xs, xec); break;
                case 3:  m = rowmax_lds<3 >(rrow, xs, xec); break;
                case 4:  m = rowmax_lds<4 >(rrow, xs, xec); break;
                case 5:  m = rowmax_lds<5 >(rrow, xs, xec); break;
                case 6:  m = rowmax_lds<6 >(rrow, xs, xec); break;
                case 7:  m = rowmax_lds<7 >(rrow, xs, xec); break;
                case 8:  m = rowmax_lds<8 >(rrow, xs, xec); break;
                case 9:  m = rowmax_lds<9 >(rrow, xs, xec); break;
                default: m = rowmax_lds<10>(rrow, xs, xec); break;
            }
            if (xempty | (wlen <= 0)) m = NEGV;
            const bool padr = (i * psh < pad_t) | ((i + 1) * psh > pad_t + roi_h);
            if (padr | padc) m = fmaxf(m, 0.0f);
            if (active) out[obase + (size_t)i * 7] = m;
        }
    }
}

extern "C" void kernel_launch(void* const* d_in, const int* in_sizes, int n_in,
                              void* d_out, int out_size, void* d_ws, size_t ws_size,
                              hipStream_t stream) {
    const float* feat = (const float*)d_in[0];
    const float* rois = (const float*)d_in[1];
    float* out = (float*)d_out;

    // 128 ROIs x 64 channel-quads; one block per (ROI, 4-channel group)
    const int blocks = 2 * 64 * 64;     // 8192
    roi_pool_kernel<<<blocks, 256, 0, stream>>>(
        feat, (const float4*)rois, out);
}